// Round 10
// baseline (49.451 us; speedup 1.0000x reference)
//
#include <hip/hip_runtime.h>

#define IMGW 28
#define OUTW 26
#define FLAT (OUTW * OUTW)
#define NCLS 10
#define WROW 28   // padded col dim of wL rows (float4-reach at c0=24 hits 26,27)

// lane = image (64 imgs/block). Waves 0..6 take 4-wide output-column strips
// (starts 0,4,...,24; wave6 masks to 2 valid cols; wave7 idles) over all 26
// rows -> no halo overfetch (all waves read the same image cache lines).
// Conv from a 4-slot rolling register row-buffer. FC weights live in LDS as
// wL[r][c][28] so each wave reads ONE float4 per (r,c) at a wave-uniform,
// 16B-aligned address (broadcast ds_read_b128, 10/body). Weight fragments are
// software-pipelined one body deep through float4 wA[10]/wB[10]: body k
// issues W(k+1) loads, FMAs from W(k) loaded last body -> ~150 VALU cycles
// cover the ~120-cycle DS latency (round 7 was serialized on this chain).
// __launch_bounds__(512,1): no VGPR cap needed -- residency is grid-limited
// (512 blocks / 256 CUs = 2 blocks/CU; 4 waves/SIMD x <=512 VGPR fits pool).
// Round 6's spill was the (512,2)=128-VGPR cap, not the structure.
__global__ __launch_bounds__(512, 1) void fused_conv_fc_kernel(
    const float* __restrict__ x,       // [B, 784]
    const float* __restrict__ conv_w,  // [3,3]
    const float* __restrict__ fc_w,    // [10, 676]
    const float* __restrict__ fc_b,    // [10]
    float* __restrict__ out)           // [B, 10]
{
    __shared__ float wL[OUTW * NCLS * WROW];   // 26*10*28*4 = 29120 B
    __shared__ float part[6][64][NCLS];        // 15360 B

    const int tid  = threadIdx.x;
    const int lane = tid & 63;
    const int wid  = __builtin_amdgcn_readfirstlane(tid >> 6);
    const int img  = blockIdx.x * 64 + lane;

    const float* ip = x + (size_t)img * (IMGW * IMGW);

    // stage fc_w -> wL[(r*10+c)*28 + cc] = fc_w[c*676 + r*26 + cc]
    for (int i = tid; i < NCLS * FLAT; i += 512) {
        int c    = i / FLAT;
        int rest = i - c * FLAT;
        int r    = rest / OUTW;
        int cc   = rest - r * OUTW;
        wL[(r * NCLS + c) * WROW + cc] = fc_w[i];
    }
    for (int i = tid; i < OUTW * NCLS * 2; i += 512) {   // zero pad cols 26,27
        int rc = i >> 1;
        wL[rc * WROW + OUTW + (i & 1)] = 0.f;
    }

    // uniform conv weights -> SGPRs
    const float cw0 = conv_w[0], cw1 = conv_w[1], cw2 = conv_w[2];
    const float cw3 = conv_w[3], cw4 = conv_w[4], cw5 = conv_w[5];
    const float cw6 = conv_w[6], cw7 = conv_w[7], cw8 = conv_w[8];

    __syncthreads();

    float acc[NCLS];
#pragma unroll
    for (int c = 0; c < NCLS; ++c) acc[c] = 0.f;

    if (wid < 7) {
        const int  c0   = (wid == 6) ? 24 : 4 * wid;  // 16B-aligned strip start
        const int  wv   = (wid == 6) ? 2  : 4;        // valid out cols
        const bool full = (wid != 6);                 // wave-uniform

        const float* wbase = &wL[c0];   // uniform per wave

        __attribute__((aligned(16))) float b0[8], b1[8], b2[8], b3[8];
        float4 wA[NCLS], wB[NCLS];

#define LOADR(BUF, RR) do {                                            \
        const float4* _p = (const float4*)(ip + (RR) * IMGW + c0);     \
        *(float4*)&BUF[0] = _p[0];                                     \
        if (full) *(float4*)&BUF[4] = _p[1];                           \
    } while (0)

#define WLOAD(WREG, R) do {                                            \
        _Pragma("unroll")                                              \
        for (int c = 0; c < NCLS; ++c)                                 \
            WREG[c] = *(const float4*)&wbase[((R) * NCLS + c) * WROW]; \
    } while (0)

        if (!full) {   // dead slots stay finite (feed masked h only)
#pragma unroll
            for (int q = 4; q < 8; ++q) { b0[q] = 0.f; b1[q] = 0.f;
                                          b2[q] = 0.f; b3[q] = 0.f; }
        }

        LOADR(b0, 0); LOADR(b1, 1); LOADR(b2, 2); LOADR(b3, 3);
        WLOAD(wA, 0);

        // body R: conv h (VALU) || issue W(R+1) ds_reads || prefetch image
        // row RL || FMA from WCUR (loaded one body ago).
#define BODY(A, B, C, L, RL, WCUR, WNEXT, R, DO_W, DO_IMG) do {        \
        float h[4];                                                    \
        _Pragma("unroll")                                              \
        for (int j = 0; j < 4; ++j) {                                  \
            float t = A[j]     * cw0 + A[j + 1] * cw1 + A[j + 2] * cw2 \
                    + B[j]     * cw3 + B[j + 1] * cw4 + B[j + 2] * cw5 \
                    + C[j]     * cw6 + C[j + 1] * cw7 + C[j + 2] * cw8;\
            t = fmaxf(t, 0.f);                                         \
            h[j] = (j >= wv) ? 0.f : t;                                \
        }                                                              \
        if (DO_W)   WLOAD(WNEXT, (R) + 1);                             \
        if (DO_IMG) LOADR(L, RL);                                      \
        _Pragma("unroll")                                              \
        for (int c = 0; c < NCLS; ++c) {                               \
            acc[c] = fmaf(h[0], WCUR[c].x, acc[c]);                    \
            acc[c] = fmaf(h[1], WCUR[c].y, acc[c]);                    \
            acc[c] = fmaf(h[2], WCUR[c].z, acc[c]);                    \
            acc[c] = fmaf(h[3], WCUR[c].w, acc[c]);                    \
        }                                                              \
    } while (0)

        int r = 0;
#pragma unroll 1
        for (int t6 = 0; t6 < 6; ++t6) {     // rows 0..23; img loads reach 27
            BODY(b0, b1, b2, b0, r + 4, wA, wB, r + 0, true, true);
            BODY(b1, b2, b3, b1, r + 5, wB, wA, r + 1, true, true);
            BODY(b2, b3, b0, b2, r + 6, wA, wB, r + 2, true, true);
            BODY(b3, b0, b1, b3, r + 7, wB, wA, r + 3, true, true);
            r += 4;
        }
        // bodies 24,25: b0..b3 hold rows 24..27; no image prefetch
        BODY(b0, b1, b2, b0, 0, wA, wB, 24, true,  false);  // loads W(25)->wB
        BODY(b1, b2, b3, b1, 0, wB, wA, 25, false, false);
#undef LOADR
#undef WLOAD
#undef BODY
    }

    if (wid >= 1 && wid < 7) {
#pragma unroll
        for (int c = 0; c < NCLS; ++c) part[wid - 1][lane][c] = acc[c];
    }
    __syncthreads();
    if (wid == 0) {
        float v[NCLS];
#pragma unroll
        for (int c = 0; c < NCLS; ++c) {
            float t = acc[c];
#pragma unroll
            for (int w = 0; w < 6; ++w) t += part[w][lane][c];
            v[c] = t + fc_b[c];
        }
        float* o = out + (size_t)img * NCLS;
#pragma unroll
        for (int q = 0; q < 5; ++q)
            *(float2*)(o + 2 * q) = make_float2(v[2 * q], v[2 * q + 1]);
    }
}

extern "C" void kernel_launch(void* const* d_in, const int* in_sizes, int n_in,
                              void* d_out, int out_size, void* d_ws, size_t ws_size,
                              hipStream_t stream) {
    const float* x      = (const float*)d_in[0];
    const float* conv_w = (const float*)d_in[1];
    const float* fc_w   = (const float*)d_in[2];
    const float* fc_b   = (const float*)d_in[3];
    float* out = (float*)d_out;

    const int nimg   = in_sizes[0] / (IMGW * IMGW);  // 32768
    const int blocks = nimg / 64;                    // 512

    hipLaunchKernelGGL(fused_conv_fc_kernel, dim3(blocks), dim3(512), 0, stream,
                       x, conv_w, fc_w, fc_b, out);
}

// Round 11
// 49.320 us; speedup vs baseline: 1.0026x; 1.0026x over previous
//
#include <hip/hip_runtime.h>

#define IMGW 28
#define OUTW 26
#define FLAT (OUTW * OUTW)
#define NCLS 10
#define WROW 28   // padded col dim of wL rows (float4-reach at c0=24 hits 26,27)

// lane = image (64 imgs/block). Waves 0..6 take 4-wide output-column strips
// (starts 0,4,...,24; wave6 masks to 2 valid cols; wave7 idles) over all 26
// rows -> no halo overfetch (all waves read the same image cache lines).
// Conv from a 4-slot rolling register row-buffer. FC weights live in LDS as
// wL[r][c][28] so each wave reads ONE float4 per (r,c) at a wave-uniform,
// 16B-aligned address (broadcast ds_read_b128, 10/body). Weight fragments are
// software-pipelined one body deep through float4 wA[10]/wB[10]: body k
// issues W(k+1) loads, FMAs from W(k) loaded last body -> ~150 VALU cycles
// cover the ~120-cycle DS latency (round 7 was serialized on this chain).
// __launch_bounds__(512,1): no VGPR cap needed -- residency is grid-limited
// (512 blocks / 256 CUs = 2 blocks/CU; 4 waves/SIMD x <=512 VGPR fits pool).
// Round 6's spill was the (512,2)=128-VGPR cap, not the structure.
__global__ __launch_bounds__(512, 1) void fused_conv_fc_kernel(
    const float* __restrict__ x,       // [B, 784]
    const float* __restrict__ conv_w,  // [3,3]
    const float* __restrict__ fc_w,    // [10, 676]
    const float* __restrict__ fc_b,    // [10]
    float* __restrict__ out)           // [B, 10]
{
    __shared__ float wL[OUTW * NCLS * WROW];   // 26*10*28*4 = 29120 B
    __shared__ float part[6][64][NCLS];        // 15360 B

    const int tid  = threadIdx.x;
    const int lane = tid & 63;
    const int wid  = __builtin_amdgcn_readfirstlane(tid >> 6);
    const int img  = blockIdx.x * 64 + lane;

    const float* ip = x + (size_t)img * (IMGW * IMGW);

    // stage fc_w -> wL[(r*10+c)*28 + cc] = fc_w[c*676 + r*26 + cc]
    for (int i = tid; i < NCLS * FLAT; i += 512) {
        int c    = i / FLAT;
        int rest = i - c * FLAT;
        int r    = rest / OUTW;
        int cc   = rest - r * OUTW;
        wL[(r * NCLS + c) * WROW + cc] = fc_w[i];
    }
    for (int i = tid; i < OUTW * NCLS * 2; i += 512) {   // zero pad cols 26,27
        int rc = i >> 1;
        wL[rc * WROW + OUTW + (i & 1)] = 0.f;
    }

    // uniform conv weights -> SGPRs
    const float cw0 = conv_w[0], cw1 = conv_w[1], cw2 = conv_w[2];
    const float cw3 = conv_w[3], cw4 = conv_w[4], cw5 = conv_w[5];
    const float cw6 = conv_w[6], cw7 = conv_w[7], cw8 = conv_w[8];

    __syncthreads();

    float acc[NCLS];
#pragma unroll
    for (int c = 0; c < NCLS; ++c) acc[c] = 0.f;

    if (wid < 7) {
        const int  c0   = (wid == 6) ? 24 : 4 * wid;  // 16B-aligned strip start
        const int  wv   = (wid == 6) ? 2  : 4;        // valid out cols
        const bool full = (wid != 6);                 // wave-uniform

        const float* wbase = &wL[c0];   // uniform per wave

        __attribute__((aligned(16))) float b0[8], b1[8], b2[8], b3[8];
        float4 wA[NCLS], wB[NCLS];

#define LOADR(BUF, RR) do {                                            \
        const float4* _p = (const float4*)(ip + (RR) * IMGW + c0);     \
        *(float4*)&BUF[0] = _p[0];                                     \
        if (full) *(float4*)&BUF[4] = _p[1];                           \
    } while (0)

#define WLOAD(WREG, R) do {                                            \
        _Pragma("unroll")                                              \
        for (int c = 0; c < NCLS; ++c)                                 \
            WREG[c] = *(const float4*)&wbase[((R) * NCLS + c) * WROW]; \
    } while (0)

        if (!full) {   // dead slots stay finite (feed masked h only)
#pragma unroll
            for (int q = 4; q < 8; ++q) { b0[q] = 0.f; b1[q] = 0.f;
                                          b2[q] = 0.f; b3[q] = 0.f; }
        }

        LOADR(b0, 0); LOADR(b1, 1); LOADR(b2, 2); LOADR(b3, 3);
        WLOAD(wA, 0);

        // body R: conv h (VALU) || issue W(R+1) ds_reads || prefetch image
        // row RL || FMA from WCUR (loaded one body ago).
#define BODY(A, B, C, L, RL, WCUR, WNEXT, R, DO_W, DO_IMG) do {        \
        float h[4];                                                    \
        _Pragma("unroll")                                              \
        for (int j = 0; j < 4; ++j) {                                  \
            float t = A[j]     * cw0 + A[j + 1] * cw1 + A[j + 2] * cw2 \
                    + B[j]     * cw3 + B[j + 1] * cw4 + B[j + 2] * cw5 \
                    + C[j]     * cw6 + C[j + 1] * cw7 + C[j + 2] * cw8;\
            t = fmaxf(t, 0.f);                                         \
            h[j] = (j >= wv) ? 0.f : t;                                \
        }                                                              \
        if (DO_W)   WLOAD(WNEXT, (R) + 1);                             \
        if (DO_IMG) LOADR(L, RL);                                      \
        _Pragma("unroll")                                              \
        for (int c = 0; c < NCLS; ++c) {                               \
            acc[c] = fmaf(h[0], WCUR[c].x, acc[c]);                    \
            acc[c] = fmaf(h[1], WCUR[c].y, acc[c]);                    \
            acc[c] = fmaf(h[2], WCUR[c].z, acc[c]);                    \
            acc[c] = fmaf(h[3], WCUR[c].w, acc[c]);                    \
        }                                                              \
    } while (0)

        int r = 0;
#pragma unroll 1
        for (int t6 = 0; t6 < 6; ++t6) {     // rows 0..23; img loads reach 27
            BODY(b0, b1, b2, b0, r + 4, wA, wB, r + 0, true, true);
            BODY(b1, b2, b3, b1, r + 5, wB, wA, r + 1, true, true);
            BODY(b2, b3, b0, b2, r + 6, wA, wB, r + 2, true, true);
            BODY(b3, b0, b1, b3, r + 7, wB, wA, r + 3, true, true);
            r += 4;
        }
        // bodies 24,25: b0..b3 hold rows 24..27; no image prefetch
        BODY(b0, b1, b2, b0, 0, wA, wB, 24, true,  false);  // loads W(25)->wB
        BODY(b1, b2, b3, b1, 0, wB, wA, 25, false, false);
#undef LOADR
#undef WLOAD
#undef BODY
    }

    if (wid >= 1 && wid < 7) {
#pragma unroll
        for (int c = 0; c < NCLS; ++c) part[wid - 1][lane][c] = acc[c];
    }
    __syncthreads();
    if (wid == 0) {
        float v[NCLS];
#pragma unroll
        for (int c = 0; c < NCLS; ++c) {
            float t = acc[c];
#pragma unroll
            for (int w = 0; w < 6; ++w) t += part[w][lane][c];
            v[c] = t + fc_b[c];
        }
        float* o = out + (size_t)img * NCLS;
#pragma unroll
        for (int q = 0; q < 5; ++q)
            *(float2*)(o + 2 * q) = make_float2(v[2 * q], v[2 * q + 1]);
    }
}

extern "C" void kernel_launch(void* const* d_in, const int* in_sizes, int n_in,
                              void* d_out, int out_size, void* d_ws, size_t ws_size,
                              hipStream_t stream) {
    const float* x      = (const float*)d_in[0];
    const float* conv_w = (const float*)d_in[1];
    const float* fc_w   = (const float*)d_in[2];
    const float* fc_b   = (const float*)d_in[3];
    float* out = (float*)d_out;

    const int nimg   = in_sizes[0] / (IMGW * IMGW);  // 32768
    const int blocks = nimg / 64;                    // 512

    hipLaunchKernelGGL(fused_conv_fc_kernel, dim3(blocks), dim3(512), 0, stream,
                       x, conv_w, fc_w, fc_b, out);
}

// Round 12
// 48.854 us; speedup vs baseline: 1.0122x; 1.0095x over previous
//
#include <hip/hip_runtime.h>

#define IMGW 28
#define OUTW 26
#define FLAT (OUTW * OUTW)
#define NCLS 10
#define WROW 28   // padded col dim of wL rows (float4-reach at c0=24 hits 26,27)

// lane = image (64 imgs/block). Waves 0..6 take 4-wide output-column strips
// (starts 0,4,...,24; wave6 masks to 2 valid cols; wave7 idles) over all 26
// rows -> no halo overfetch (all waves read the same image cache lines).
// Conv from a 4-slot rolling register row-buffer. FC weights live in LDS as
// wL[r][c][28] so each wave reads ONE float4 per (r,c) at a wave-uniform,
// 16B-aligned address (broadcast ds_read_b128, 10/body). Weight fragments are
// software-pipelined one body deep through float4 wA[10]/wB[10]: body k
// issues W(k+1) loads, FMAs from W(k) loaded last body -> ~150 VALU cycles
// cover the ~120-cycle DS latency (round 7 was serialized on this chain).
// __launch_bounds__(512,1): no VGPR cap needed -- residency is grid-limited
// (512 blocks / 256 CUs = 2 blocks/CU; 4 waves/SIMD x <=512 VGPR fits pool).
// Round 6's spill was the (512,2)=128-VGPR cap, not the structure.
__global__ __launch_bounds__(512, 1) void fused_conv_fc_kernel(
    const float* __restrict__ x,       // [B, 784]
    const float* __restrict__ conv_w,  // [3,3]
    const float* __restrict__ fc_w,    // [10, 676]
    const float* __restrict__ fc_b,    // [10]
    float* __restrict__ out)           // [B, 10]
{
    __shared__ float wL[OUTW * NCLS * WROW];   // 26*10*28*4 = 29120 B
    __shared__ float part[6][64][NCLS];        // 15360 B

    const int tid  = threadIdx.x;
    const int lane = tid & 63;
    const int wid  = __builtin_amdgcn_readfirstlane(tid >> 6);
    const int img  = blockIdx.x * 64 + lane;

    const float* ip = x + (size_t)img * (IMGW * IMGW);

    // stage fc_w -> wL[(r*10+c)*28 + cc] = fc_w[c*676 + r*26 + cc]
    for (int i = tid; i < NCLS * FLAT; i += 512) {
        int c    = i / FLAT;
        int rest = i - c * FLAT;
        int r    = rest / OUTW;
        int cc   = rest - r * OUTW;
        wL[(r * NCLS + c) * WROW + cc] = fc_w[i];
    }
    for (int i = tid; i < OUTW * NCLS * 2; i += 512) {   // zero pad cols 26,27
        int rc = i >> 1;
        wL[rc * WROW + OUTW + (i & 1)] = 0.f;
    }

    // uniform conv weights -> SGPRs
    const float cw0 = conv_w[0], cw1 = conv_w[1], cw2 = conv_w[2];
    const float cw3 = conv_w[3], cw4 = conv_w[4], cw5 = conv_w[5];
    const float cw6 = conv_w[6], cw7 = conv_w[7], cw8 = conv_w[8];

    __syncthreads();

    float acc[NCLS];
#pragma unroll
    for (int c = 0; c < NCLS; ++c) acc[c] = 0.f;

    if (wid < 7) {
        const int  c0   = (wid == 6) ? 24 : 4 * wid;  // 16B-aligned strip start
        const int  wv   = (wid == 6) ? 2  : 4;        // valid out cols
        const bool full = (wid != 6);                 // wave-uniform

        const float* wbase = &wL[c0];   // uniform per wave

        __attribute__((aligned(16))) float b0[8], b1[8], b2[8], b3[8];
        float4 wA[NCLS], wB[NCLS];

#define LOADR(BUF, RR) do {                                            \
        const float4* _p = (const float4*)(ip + (RR) * IMGW + c0);     \
        *(float4*)&BUF[0] = _p[0];                                     \
        if (full) *(float4*)&BUF[4] = _p[1];                           \
    } while (0)

#define WLOAD(WREG, R) do {                                            \
        _Pragma("unroll")                                              \
        for (int c = 0; c < NCLS; ++c)                                 \
            WREG[c] = *(const float4*)&wbase[((R) * NCLS + c) * WROW]; \
    } while (0)

        if (!full) {   // dead slots stay finite (feed masked h only)
#pragma unroll
            for (int q = 4; q < 8; ++q) { b0[q] = 0.f; b1[q] = 0.f;
                                          b2[q] = 0.f; b3[q] = 0.f; }
        }

        LOADR(b0, 0); LOADR(b1, 1); LOADR(b2, 2); LOADR(b3, 3);
        WLOAD(wA, 0);

        // body R: conv h (VALU) || issue W(R+1) ds_reads || prefetch image
        // row RL || FMA from WCUR (loaded one body ago).
#define BODY(A, B, C, L, RL, WCUR, WNEXT, R, DO_W, DO_IMG) do {        \
        float h[4];                                                    \
        _Pragma("unroll")                                              \
        for (int j = 0; j < 4; ++j) {                                  \
            float t = A[j]     * cw0 + A[j + 1] * cw1 + A[j + 2] * cw2 \
                    + B[j]     * cw3 + B[j + 1] * cw4 + B[j + 2] * cw5 \
                    + C[j]     * cw6 + C[j + 1] * cw7 + C[j + 2] * cw8;\
            t = fmaxf(t, 0.f);                                         \
            h[j] = (j >= wv) ? 0.f : t;                                \
        }                                                              \
        if (DO_W)   WLOAD(WNEXT, (R) + 1);                             \
        if (DO_IMG) LOADR(L, RL);                                      \
        _Pragma("unroll")                                              \
        for (int c = 0; c < NCLS; ++c) {                               \
            acc[c] = fmaf(h[0], WCUR[c].x, acc[c]);                    \
            acc[c] = fmaf(h[1], WCUR[c].y, acc[c]);                    \
            acc[c] = fmaf(h[2], WCUR[c].z, acc[c]);                    \
            acc[c] = fmaf(h[3], WCUR[c].w, acc[c]);                    \
        }                                                              \
    } while (0)

        int r = 0;
#pragma unroll 1
        for (int t6 = 0; t6 < 6; ++t6) {     // rows 0..23; img loads reach 27
            BODY(b0, b1, b2, b0, r + 4, wA, wB, r + 0, true, true);
            BODY(b1, b2, b3, b1, r + 5, wB, wA, r + 1, true, true);
            BODY(b2, b3, b0, b2, r + 6, wA, wB, r + 2, true, true);
            BODY(b3, b0, b1, b3, r + 7, wB, wA, r + 3, true, true);
            r += 4;
        }
        // bodies 24,25: b0..b3 hold rows 24..27; no image prefetch
        BODY(b0, b1, b2, b0, 0, wA, wB, 24, true,  false);  // loads W(25)->wB
        BODY(b1, b2, b3, b1, 0, wB, wA, 25, false, false);
#undef LOADR
#undef WLOAD
#undef BODY
    }

    if (wid >= 1 && wid < 7) {
#pragma unroll
        for (int c = 0; c < NCLS; ++c) part[wid - 1][lane][c] = acc[c];
    }
    __syncthreads();
    if (wid == 0) {
        float v[NCLS];
#pragma unroll
        for (int c = 0; c < NCLS; ++c) {
            float t = acc[c];
#pragma unroll
            for (int w = 0; w < 6; ++w) t += part[w][lane][c];
            v[c] = t + fc_b[c];
        }
        float* o = out + (size_t)img * NCLS;
#pragma unroll
        for (int q = 0; q < 5; ++q)
            *(float2*)(o + 2 * q) = make_float2(v[2 * q], v[2 * q + 1]);
    }
}

extern "C" void kernel_launch(void* const* d_in, const int* in_sizes, int n_in,
                              void* d_out, int out_size, void* d_ws, size_t ws_size,
                              hipStream_t stream) {
    const float* x      = (const float*)d_in[0];
    const float* conv_w = (const float*)d_in[1];
    const float* fc_w   = (const float*)d_in[2];
    const float* fc_b   = (const float*)d_in[3];
    float* out = (float*)d_out;

    const int nimg   = in_sizes[0] / (IMGW * IMGW);  // 32768
    const int blocks = nimg / 64;                    // 512

    hipLaunchKernelGGL(fused_conv_fc_kernel, dim3(blocks), dim3(512), 0, stream,
                       x, conv_w, fc_w, fc_b, out);
}